// Round 5
// baseline (218.293 us; speedup 1.0000x reference)
//
#include <hip/hip_runtime.h>
#include <hip/hip_fp16.h>

#define NBINS 255
#define NPAIRS 32
#define BIGF 3.0e38f

// ws layout (bytes):
//   [0      ,  65536) : E   [64][256] fp32 natural (tail = BIGF)
//   [65536  , 131072) : PE  [64][256] fp32 natural
//   [131072 , 163840) : W16 [64][256] fp16, PRE-SHIFTED: W16[f][c] = w[f][c<255?c+1:0]
//   [163840 ,4358144) : T16 [32][256][256] fp16, PRE-SHIFTED both dims (if ws allows)

__global__ void ebm_prep_edges(const float* __restrict__ edges,
                               const float* __restrict__ pair_edges,
                               const float* __restrict__ w,
                               float* __restrict__ ws) {
    int tid = blockIdx.x * blockDim.x + threadIdx.x;  // 16384 threads
    float* E   = ws;
    float* PE  = ws + 16384;
    __half* W  = (__half*)(ws + 32768);
    int f = tid >> 8, j = tid & 255;
    E[tid]  = (j < NBINS) ? edges[f * NBINS + j]      : BIGF;
    PE[tid] = (j < NBINS) ? pair_edges[f * NBINS + j] : BIGF;
    int src = (j < 255) ? j + 1 : 0;                  // pre-shifted bin remap
    W[tid]  = __float2half(w[f * 256 + src]);
}

__global__ void ebm_prep_tables(const float* __restrict__ tables,
                                unsigned short* __restrict__ o) {
    int i = blockIdx.x * blockDim.x + threadIdx.x;    // 2097152 threads
    int b = i & 255, a = (i >> 8) & 255, p = i >> 16;
    int ra = (a < 255) ? a + 1 : 0;
    int rb = (b < 255) ? b + 1 : 0;
    float v = tables[(p << 16) + (ra << 8) + rb];
    o[i] = __half_as_ushort(__float2half(v));
}

// lanes with (lane&mask)==0 carry a's stream, others b's; summed with partner
__device__ __forceinline__ float merge2(float a, float b, int mask, int lane) {
    bool lo = (lane & mask) == 0;
    float send = lo ? b : a;
    float recv = __shfl_xor(send, mask, 64);
    float keep = lo ? a : b;
    return keep + recv;
}

__global__ __launch_bounds__(1024, 4) void ebm_main(
    const float* __restrict__ x,
    const int*   __restrict__ pairs,
    const float* __restrict__ tables_f32,
    const float* __restrict__ bias,
    const float* __restrict__ ws,
    const __half* __restrict__ T16,
    int useT16,
    float*       __restrict__ out) {

    // 160 KiB; edge arrays full-float xor-swizzled: phys index = k ^ f
    __shared__ float  sE[16384];
    __shared__ float  sPE[16384];
    __shared__ __half sW[16384];   // natural order, pre-shifted values

    const float* E  = ws;
    const float* PE = ws + 16384;
    const unsigned int* W32 = (const unsigned int*)(ws + 32768);

    int tid  = threadIdx.x;
    int lane = tid & 63;           // lane == feature f

    for (int i = tid; i < 16384; i += 1024) {
        int f = i >> 8, k = i & 255;
        sE[(f << 8) + (k ^ f)]  = E[i];
        sPE[(f << 8) + (k ^ f)] = PE[i];
    }
    {
        unsigned int* sW32 = (unsigned int*)sW;
        for (int i = tid; i < 8192; i += 1024) sW32[i] = W32[i];
    }

    // coarse edges (positions 16j+15, j=0..14) from ws natural arrays
    float cu[15], cp[15];
#pragma unroll
    for (int j = 0; j < 15; ++j) {
        cu[j] = E[lane * 256 + 16 * j + 15];
        cp[j] = PE[lane * 256 + 16 * j + 15];
    }

    int pa = 0, pb = 0;
    if (lane < NPAIRS) { pa = pairs[2 * lane]; pb = pairs[2 * lane + 1]; }
    bool act = false;
#pragma unroll 1
    for (int k = 0; k < 2 * NPAIRS; ++k) act = act || (pairs[k] == lane);
    float bias0 = bias[0];

    __syncthreads();

    // per-lane swizzle constants
    const int fbase = lane << 8;          // float index of feature row
    const int fh    = lane & 48;          // xor for mid high nibble
    const int ci0   = 3  ^ (lane & 15);   // mid element offsets (low nibble)
    const int ci1   = 7  ^ (lane & 15);
    const int ci2   = 11 ^ (lane & 15);
    const int fq    = lane >> 2;          // xor for fine float4 slot (0..15)

    const float4* sE4  = (const float4*)sE;
    const float4* sPE4 = (const float4*)sPE;

    int gw = blockIdx.x * 16 + (tid >> 6);   // 512 blocks * 16 waves = 8192 waves
    int row0 = gw * 32;                      // 32 rows/wave = 4 iters x 8 rows

    float xv[8];
#pragma unroll
    for (int u = 0; u < 8; ++u) xv[u] = x[(row0 + u) * 64 + lane];

#pragma unroll 1
    for (int it = 0; it < 4; ++it) {
        int rowbase = row0 + it * 8;

        // prefetch next 8 rows
        float xn[8];
        int nb = (it < 3) ? (rowbase + 8) : rowbase;
#pragma unroll
        for (int u = 0; u < 8; ++u) xn[u] = x[(nb + u) * 64 + lane];

        // ================= PAIR SEARCH FIRST =================
        int pidx[8] = {0, 0, 0, 0, 0, 0, 0, 0};
        if (act) {
            int t2[8];
#pragma unroll
            for (int u = 0; u < 8; ++u) {
                int tt = 0;
#pragma unroll
                for (int j = 0; j < 15; ++j) tt += (xv[u] >= cp[j]);
                t2[u] = tt;
            }
            float mb[8][3];
#pragma unroll
            for (int u = 0; u < 8; ++u) {
                int tb = fbase + ((t2[u] << 4) ^ fh);
                mb[u][0] = sPE[tb + ci0];
                mb[u][1] = sPE[tb + ci1];
                mb[u][2] = sPE[tb + ci2];
            }
            float4 gv[8];
#pragma unroll
            for (int u = 0; u < 8; ++u) {
                int m = (xv[u] >= mb[u][0]) + (xv[u] >= mb[u][1]) + (xv[u] >= mb[u][2]);
                pidx[u] = (t2[u] << 4) + (m << 2);
                gv[u] = sPE4[(lane << 6) + (((t2[u] << 2) + m) ^ fq)];
            }
#pragma unroll
            for (int u = 0; u < 8; ++u) {
                pidx[u] += (xv[u] >= gv[u].x) + (xv[u] >= gv[u].y) +
                           (xv[u] >= gv[u].z) + (xv[u] >= gv[u].w);
            }
        }

        // packed exchange (8 rows as 2 words of 4x8-bit)
        int pk0 = pidx[0] | (pidx[1] << 8) | (pidx[2] << 16) | (pidx[3] << 24);
        int pk1 = pidx[4] | (pidx[5] << 8) | (pidx[6] << 16) | (pidx[7] << 24);
        int lk0 = __shfl(pk0, pa, 64), lk1 = __shfl(pk1, pa, 64);
        int rk0 = __shfl(pk0, pb, 64), rk1 = __shfl(pk1, pb, 64);

        // issue all 8 table gathers NOW; latency hides under unary search
        float tv[8] = {0.f, 0.f, 0.f, 0.f, 0.f, 0.f, 0.f, 0.f};
        if (lane < NPAIRS) {
            if (useT16) {
#pragma unroll
                for (int u = 0; u < 4; ++u) {
                    int li = (lk0 >> (8 * u)) & 255, ri = (rk0 >> (8 * u)) & 255;
                    tv[u] = __half2float(T16[(lane << 16) + (li << 8) + ri]);
                }
#pragma unroll
                for (int u = 0; u < 4; ++u) {
                    int li = (lk1 >> (8 * u)) & 255, ri = (rk1 >> (8 * u)) & 255;
                    tv[4 + u] = __half2float(T16[(lane << 16) + (li << 8) + ri]);
                }
            } else {
#pragma unroll
                for (int u = 0; u < 4; ++u) {
                    int li = (lk0 >> (8 * u)) & 255, ri = (rk0 >> (8 * u)) & 255;
                    int lb = (li < 255) ? li + 1 : 0, rb = (ri < 255) ? ri + 1 : 0;
                    tv[u] = tables_f32[(lane << 16) + (lb << 8) + rb];
                }
#pragma unroll
                for (int u = 0; u < 4; ++u) {
                    int li = (lk1 >> (8 * u)) & 255, ri = (rk1 >> (8 * u)) & 255;
                    int lb = (li < 255) ? li + 1 : 0, rb = (ri < 255) ? ri + 1 : 0;
                    tv[4 + u] = tables_f32[(lane << 16) + (lb << 8) + rb];
                }
            }
        }

        // ================= UNARY SEARCH (overlaps gather latency) =================
        int t[8];
#pragma unroll
        for (int u = 0; u < 8; ++u) {
            int tt = 0;
#pragma unroll
            for (int j = 0; j < 15; ++j) tt += (xv[u] >= cu[j]);
            t[u] = tt;
        }
        float ma[8][3];
#pragma unroll
        for (int u = 0; u < 8; ++u) {
            int tb = fbase + ((t[u] << 4) ^ fh);
            ma[u][0] = sE[tb + ci0];
            ma[u][1] = sE[tb + ci1];
            ma[u][2] = sE[tb + ci2];
        }
        int cpart[8];
        float4 fv[8];
#pragma unroll
        for (int u = 0; u < 8; ++u) {
            int m = (xv[u] >= ma[u][0]) + (xv[u] >= ma[u][1]) + (xv[u] >= ma[u][2]);
            cpart[u] = (t[u] << 4) + (m << 2);
            fv[u] = sE4[(lane << 6) + (((t[u] << 2) + m) ^ fq)];
        }
        float wv[8];
#pragma unroll
        for (int u = 0; u < 8; ++u) {
            int cnt = (xv[u] >= fv[u].x) + (xv[u] >= fv[u].y) +
                      (xv[u] >= fv[u].z) + (xv[u] >= fv[u].w);
            int c = cpart[u] + cnt;          // raw count 0..255; sW pre-shifted
            wv[u] = __half2float(sW[fbase + c]);
        }

        // ================= REDUCE 8 ROWS: 10 shuffles =================
        float s0 = wv[0] + tv[0], s1 = wv[1] + tv[1];
        float s2 = wv[2] + tv[2], s3 = wv[3] + tv[3];
        float s4 = wv[4] + tv[4], s5 = wv[5] + tv[5];
        float s6 = wv[6] + tv[6], s7 = wv[7] + tv[7];

        float m01 = merge2(s0, s1, 1, lane);
        float m23 = merge2(s2, s3, 1, lane);
        float m45 = merge2(s4, s5, 1, lane);
        float m67 = merge2(s6, s7, 1, lane);
        float q0  = merge2(m01, m23, 2, lane);
        float q1  = merge2(m45, m67, 2, lane);
        float z   = merge2(q0, q1, 4, lane);
        z += __shfl_xor(z, 8, 64);
        z += __shfl_xor(z, 16, 64);
        z += __shfl_xor(z, 32, 64);

        if (lane < 8) {
            out[rowbase + lane] = 1.0f / (1.0f + __expf(-(z + bias0)));
        }

#pragma unroll
        for (int u = 0; u < 8; ++u) xv[u] = xn[u];
    }
}

extern "C" void kernel_launch(void* const* d_in, const int* in_sizes, int n_in,
                              void* d_out, int out_size, void* d_ws, size_t ws_size,
                              hipStream_t stream) {
    const float* x          = (const float*)d_in[0];
    const float* edges      = (const float*)d_in[1];
    const float* w          = (const float*)d_in[2];
    const float* pair_edges = (const float*)d_in[3];
    const int*   pairs      = (const int*)d_in[4];
    const float* tables     = (const float*)d_in[5];
    const float* bias       = (const float*)d_in[6];
    float* out = (float*)d_out;
    float* ws  = (float*)d_ws;

    int useT16 = (ws_size >= (size_t)4358144) ? 1 : 0;
    __half* T16 = (__half*)((char*)d_ws + 163840);

    ebm_prep_edges<<<64, 256, 0, stream>>>(edges, pair_edges, w, ws);
    if (useT16) {
        ebm_prep_tables<<<2048, 1024, 0, stream>>>(tables, (unsigned short*)T16);
    }
    ebm_main<<<512, 1024, 0, stream>>>(x, pairs, tables, bias, ws, T16, useT16, out);
}

// Round 6
// 216.003 us; speedup vs baseline: 1.0106x; 1.0106x over previous
//
#include <hip/hip_runtime.h>
#include <hip/hip_fp16.h>

#define NBINS 255
#define NPAIRS 32
#define BIGF 3.0e38f

// ws layout (bytes):
//   [0      ,  65536) : E   [64][256] fp32 natural (tail = BIGF)
//   [65536  , 131072) : PE  [64][256] fp32 natural
//   [131072 , 163840) : W16 [64][256] fp16, PRE-SHIFTED: W16[f][c] = w[f][c<255?c+1:0]
//   [163840 ,4358144) : T16 [32][256][256] fp16, PRE-SHIFTED both dims (if ws allows)

__global__ void ebm_prep_edges(const float* __restrict__ edges,
                               const float* __restrict__ pair_edges,
                               const float* __restrict__ w,
                               float* __restrict__ ws) {
    int tid = blockIdx.x * blockDim.x + threadIdx.x;  // 16384 threads
    float* E   = ws;
    float* PE  = ws + 16384;
    __half* W  = (__half*)(ws + 32768);
    int f = tid >> 8, j = tid & 255;
    E[tid]  = (j < NBINS) ? edges[f * NBINS + j]      : BIGF;
    PE[tid] = (j < NBINS) ? pair_edges[f * NBINS + j] : BIGF;
    int src = (j < 255) ? j + 1 : 0;                  // pre-shifted bin remap
    W[tid]  = __float2half(w[f * 256 + src]);
}

__global__ void ebm_prep_tables(const float* __restrict__ tables,
                                unsigned short* __restrict__ o) {
    int i = blockIdx.x * blockDim.x + threadIdx.x;    // 2097152 threads
    int b = i & 255, a = (i >> 8) & 255, p = i >> 16;
    int ra = (a < 255) ? a + 1 : 0;
    int rb = (b < 255) ? b + 1 : 0;
    float v = tables[(p << 16) + (ra << 8) + rb];
    o[i] = __half_as_ushort(__float2half(v));
}

// lanes with (lane&mask)==0 carry a's stream, others b's; summed with partner
__device__ __forceinline__ float merge2(float a, float b, int mask, int lane) {
    bool lo = (lane & mask) == 0;
    float send = lo ? b : a;
    float recv = __shfl_xor(send, mask, 64);
    float keep = lo ? a : b;
    return keep + recv;
}

// same, but xor-partner exchange done on the VALU pipe via DPP quad_perm.
// MASK=1 -> quad_perm [1,0,3,2] = 0xB1 ; MASK=2 -> quad_perm [2,3,0,1] = 0x4E
template<int MASK, int CTRL>
__device__ __forceinline__ float merge2_dpp(float a, float b, int lane) {
    bool lo = (lane & MASK) == 0;
    float send = lo ? b : a;
    float recv = __int_as_float(
        __builtin_amdgcn_update_dpp(0, __float_as_int(send), CTRL, 0xF, 0xF, true));
    float keep = lo ? a : b;
    return keep + recv;
}

__global__ __attribute__((amdgpu_waves_per_eu(4, 4)))
__launch_bounds__(1024) void ebm_main(
    const float* __restrict__ x,
    const int*   __restrict__ pairs,
    const float* __restrict__ tables_f32,
    const float* __restrict__ bias,
    const float* __restrict__ ws,
    const __half* __restrict__ T16,
    int useT16,
    float*       __restrict__ out) {

    // 160 KiB; edge arrays full-float xor-swizzled: phys index = k ^ f
    __shared__ float  sE[16384];
    __shared__ float  sPE[16384];
    __shared__ __half sW[16384];   // natural order, pre-shifted values

    const float* E  = ws;
    const float* PE = ws + 16384;
    const unsigned int* W32 = (const unsigned int*)(ws + 32768);

    int tid  = threadIdx.x;
    int lane = tid & 63;           // lane == feature f

    for (int i = tid; i < 16384; i += 1024) {
        int f = i >> 8, k = i & 255;
        sE[(f << 8) + (k ^ f)]  = E[i];
        sPE[(f << 8) + (k ^ f)] = PE[i];
    }
    {
        unsigned int* sW32 = (unsigned int*)sW;
        for (int i = tid; i < 8192; i += 1024) sW32[i] = W32[i];
    }

    // coarse edges (positions 16j+15, j=0..14) from ws natural arrays
    float cu[15], cp[15];
#pragma unroll
    for (int j = 0; j < 15; ++j) {
        cu[j] = E[lane * 256 + 16 * j + 15];
        cp[j] = PE[lane * 256 + 16 * j + 15];
    }

    int pa = 0, pb = 0;
    if (lane < NPAIRS) { pa = pairs[2 * lane]; pb = pairs[2 * lane + 1]; }
    bool act = false;
#pragma unroll 1
    for (int k = 0; k < 2 * NPAIRS; ++k) act = act || (pairs[k] == lane);
    float bias0 = bias[0];

    __syncthreads();

    // per-lane swizzle constants
    const int fbase = lane << 8;          // float index of feature row
    const int fh    = lane & 48;          // xor for mid high nibble
    const int ci0   = 3  ^ (lane & 15);   // mid element offsets (low nibble)
    const int ci1   = 7  ^ (lane & 15);
    const int ci2   = 11 ^ (lane & 15);
    const int fq    = lane >> 2;          // xor for fine float4 slot (0..15)

    const float4* sE4  = (const float4*)sE;
    const float4* sPE4 = (const float4*)sPE;

    int gw = blockIdx.x * 16 + (tid >> 6);   // 512 blocks * 16 waves = 8192 waves
    int row0 = gw * 32;                      // 32 rows/wave = 4 iters x 8 rows

    float xv[8];
#pragma unroll
    for (int u = 0; u < 8; ++u) xv[u] = x[(row0 + u) * 64 + lane];

#pragma unroll 1
    for (int it = 0; it < 4; ++it) {
        int rowbase = row0 + it * 8;

        // prefetch next 8 rows
        float xn[8];
        int nb = (it < 3) ? (rowbase + 8) : rowbase;
#pragma unroll
        for (int u = 0; u < 8; ++u) xn[u] = x[(nb + u) * 64 + lane];

        // ================= PAIR SEARCH FIRST =================
        int pidx[8] = {0, 0, 0, 0, 0, 0, 0, 0};
        if (act) {
            int t2[8];
#pragma unroll
            for (int u = 0; u < 8; ++u) {
                int tt = 0;
#pragma unroll
                for (int j = 0; j < 15; ++j) tt += (xv[u] >= cp[j]);
                t2[u] = tt;
            }
            float mb[8][3];
#pragma unroll
            for (int u = 0; u < 8; ++u) {
                int tb = fbase + ((t2[u] << 4) ^ fh);
                mb[u][0] = sPE[tb + ci0];
                mb[u][1] = sPE[tb + ci1];
                mb[u][2] = sPE[tb + ci2];
            }
            float4 gv[8];
#pragma unroll
            for (int u = 0; u < 8; ++u) {
                int m = (xv[u] >= mb[u][0]) + (xv[u] >= mb[u][1]) + (xv[u] >= mb[u][2]);
                pidx[u] = (t2[u] << 4) + (m << 2);
                gv[u] = sPE4[(lane << 6) + (((t2[u] << 2) + m) ^ fq)];
            }
#pragma unroll
            for (int u = 0; u < 8; ++u) {
                pidx[u] += (xv[u] >= gv[u].x) + (xv[u] >= gv[u].y) +
                           (xv[u] >= gv[u].z) + (xv[u] >= gv[u].w);
            }
        }

        // packed exchange (8 rows as 2 words of 4x8-bit)
        int pk0 = pidx[0] | (pidx[1] << 8) | (pidx[2] << 16) | (pidx[3] << 24);
        int pk1 = pidx[4] | (pidx[5] << 8) | (pidx[6] << 16) | (pidx[7] << 24);
        int lk0 = __shfl(pk0, pa, 64), lk1 = __shfl(pk1, pa, 64);
        int rk0 = __shfl(pk0, pb, 64), rk1 = __shfl(pk1, pb, 64);

        // issue all 8 table gathers NOW; latency hides under unary search
        float tv[8] = {0.f, 0.f, 0.f, 0.f, 0.f, 0.f, 0.f, 0.f};
        if (lane < NPAIRS) {
            if (useT16) {
#pragma unroll
                for (int u = 0; u < 4; ++u) {
                    int li = (lk0 >> (8 * u)) & 255, ri = (rk0 >> (8 * u)) & 255;
                    tv[u] = __half2float(T16[(lane << 16) + (li << 8) + ri]);
                }
#pragma unroll
                for (int u = 0; u < 4; ++u) {
                    int li = (lk1 >> (8 * u)) & 255, ri = (rk1 >> (8 * u)) & 255;
                    tv[4 + u] = __half2float(T16[(lane << 16) + (li << 8) + ri]);
                }
            } else {
#pragma unroll
                for (int u = 0; u < 4; ++u) {
                    int li = (lk0 >> (8 * u)) & 255, ri = (rk0 >> (8 * u)) & 255;
                    int lb = (li < 255) ? li + 1 : 0, rb = (ri < 255) ? ri + 1 : 0;
                    tv[u] = tables_f32[(lane << 16) + (lb << 8) + rb];
                }
#pragma unroll
                for (int u = 0; u < 4; ++u) {
                    int li = (lk1 >> (8 * u)) & 255, ri = (rk1 >> (8 * u)) & 255;
                    int lb = (li < 255) ? li + 1 : 0, rb = (ri < 255) ? ri + 1 : 0;
                    tv[4 + u] = tables_f32[(lane << 16) + (lb << 8) + rb];
                }
            }
        }

        // ================= UNARY SEARCH (overlaps gather latency) =================
        int t[8];
#pragma unroll
        for (int u = 0; u < 8; ++u) {
            int tt = 0;
#pragma unroll
            for (int j = 0; j < 15; ++j) tt += (xv[u] >= cu[j]);
            t[u] = tt;
        }
        float ma[8][3];
#pragma unroll
        for (int u = 0; u < 8; ++u) {
            int tb = fbase + ((t[u] << 4) ^ fh);
            ma[u][0] = sE[tb + ci0];
            ma[u][1] = sE[tb + ci1];
            ma[u][2] = sE[tb + ci2];
        }
        int cpart[8];
        float4 fv[8];
#pragma unroll
        for (int u = 0; u < 8; ++u) {
            int m = (xv[u] >= ma[u][0]) + (xv[u] >= ma[u][1]) + (xv[u] >= ma[u][2]);
            cpart[u] = (t[u] << 4) + (m << 2);
            fv[u] = sE4[(lane << 6) + (((t[u] << 2) + m) ^ fq)];
        }
        float wv[8];
#pragma unroll
        for (int u = 0; u < 8; ++u) {
            int cnt = (xv[u] >= fv[u].x) + (xv[u] >= fv[u].y) +
                      (xv[u] >= fv[u].z) + (xv[u] >= fv[u].w);
            int c = cpart[u] + cnt;          // raw count 0..255; sW pre-shifted
            wv[u] = __half2float(sW[fbase + c]);
        }

        // ====== REDUCE 8 ROWS: levels 1,2 on VALU (DPP), 4..32 via shfl ======
        float s0 = wv[0] + tv[0], s1 = wv[1] + tv[1];
        float s2 = wv[2] + tv[2], s3 = wv[3] + tv[3];
        float s4 = wv[4] + tv[4], s5 = wv[5] + tv[5];
        float s6 = wv[6] + tv[6], s7 = wv[7] + tv[7];

        float m01 = merge2_dpp<1, 0xB1>(s0, s1, lane);
        float m23 = merge2_dpp<1, 0xB1>(s2, s3, lane);
        float m45 = merge2_dpp<1, 0xB1>(s4, s5, lane);
        float m67 = merge2_dpp<1, 0xB1>(s6, s7, lane);
        float q0  = merge2_dpp<2, 0x4E>(m01, m23, lane);
        float q1  = merge2_dpp<2, 0x4E>(m45, m67, lane);
        float z   = merge2(q0, q1, 4, lane);
        z += __shfl_xor(z, 8, 64);
        z += __shfl_xor(z, 16, 64);
        z += __shfl_xor(z, 32, 64);

        if (lane < 8) {
            out[rowbase + lane] = 1.0f / (1.0f + __expf(-(z + bias0)));
        }

#pragma unroll
        for (int u = 0; u < 8; ++u) xv[u] = xn[u];
    }
}

extern "C" void kernel_launch(void* const* d_in, const int* in_sizes, int n_in,
                              void* d_out, int out_size, void* d_ws, size_t ws_size,
                              hipStream_t stream) {
    const float* x          = (const float*)d_in[0];
    const float* edges      = (const float*)d_in[1];
    const float* w          = (const float*)d_in[2];
    const float* pair_edges = (const float*)d_in[3];
    const int*   pairs      = (const int*)d_in[4];
    const float* tables     = (const float*)d_in[5];
    const float* bias       = (const float*)d_in[6];
    float* out = (float*)d_out;
    float* ws  = (float*)d_ws;

    int useT16 = (ws_size >= (size_t)4358144) ? 1 : 0;
    __half* T16 = (__half*)((char*)d_ws + 163840);

    ebm_prep_edges<<<64, 256, 0, stream>>>(edges, pair_edges, w, ws);
    if (useT16) {
        ebm_prep_tables<<<2048, 1024, 0, stream>>>(tables, (unsigned short*)T16);
    }
    ebm_main<<<512, 1024, 0, stream>>>(x, pairs, tables, bias, ws, T16, useT16, out);
}

// Round 7
// 193.650 us; speedup vs baseline: 1.1273x; 1.1154x over previous
//
#include <hip/hip_runtime.h>
#include <hip/hip_fp16.h>

#define NBINS 255
#define NPAIRS 32
#define BIGF 3.0e38f

// ws layout (float index):
//   [0     ,16384) : E    [64][256] fp32, tail BIGF
//   [16384 ,32768) : PE   [64][256]
//   [32768 ,36864) : M4E  [64][16] float4 {e[4j+3]} j=4t+c  (idx>=255 -> BIGF)
//   [36864 ,40960) : M4P
//   [40960 ,41984) : CU16 [64][16] coarse e[16j+15], j=15 pad BIGF
//   [41984 ,43008) : CP16
//   [43008 ,51200) : W16g [64][256] fp16 PRE-SHIFTED (8192 floats of storage)
//   byte 204800 .. : T16  [32][256][256] fp16 PRE-SHIFTED (needs ws >= 4399104 B)

__global__ void ebm_prep(const float* __restrict__ edges,
                         const float* __restrict__ pair_edges,
                         const float* __restrict__ w,
                         float* __restrict__ ws) {
    int tid = blockIdx.x * blockDim.x + threadIdx.x;  // 16384 threads
    int f = tid >> 8, j = tid & 255;
    float* E  = ws;
    float* PE = ws + 16384;
    float* ME = ws + 32768;
    float* MP = ws + 36864;
    float* CU = ws + 40960;
    float* CP = ws + 41984;
    __half* W = (__half*)(ws + 43008);
    E[tid]  = (j < NBINS) ? edges[f * NBINS + j]      : BIGF;
    PE[tid] = (j < NBINS) ? pair_edges[f * NBINS + j] : BIGF;
    int src = (j < 255) ? j + 1 : 0;
    W[tid]  = __float2half(w[f * 256 + src]);
    if (j < 64) {
        int idx = 4 * j + 3;   // j=4t+c -> e[16t+4c+3]
        ME[f * 64 + j] = (idx < NBINS) ? edges[f * NBINS + idx]      : BIGF;
        MP[f * 64 + j] = (idx < NBINS) ? pair_edges[f * NBINS + idx] : BIGF;
    }
    if (j < 16) {
        CU[f * 16 + j] = (j < 15) ? edges[f * NBINS + 16 * j + 15]      : BIGF;
        CP[f * 16 + j] = (j < 15) ? pair_edges[f * NBINS + 16 * j + 15] : BIGF;
    }
}

__global__ void ebm_prep_tables(const float* __restrict__ tables,
                                unsigned short* __restrict__ o) {
    int i = blockIdx.x * blockDim.x + threadIdx.x;    // 2097152 threads
    int b = i & 255, a = (i >> 8) & 255, p = i >> 16;
    int ra = (a < 255) ? a + 1 : 0;
    int rb = (b < 255) ? b + 1 : 0;
    o[i] = __half_as_ushort(__float2half(tables[(p << 16) + (ra << 8) + rb]));
}

// uniform 16-way register select: s is wave-uniform -> 15 v_cndmask w/ scalar masks
__device__ __forceinline__ unsigned pick16(const unsigned* pw, int s) {
    unsigned v01 = (s & 1) ? pw[1]  : pw[0];
    unsigned v23 = (s & 1) ? pw[3]  : pw[2];
    unsigned v45 = (s & 1) ? pw[5]  : pw[4];
    unsigned v67 = (s & 1) ? pw[7]  : pw[6];
    unsigned v89 = (s & 1) ? pw[9]  : pw[8];
    unsigned vab = (s & 1) ? pw[11] : pw[10];
    unsigned vcd = (s & 1) ? pw[13] : pw[12];
    unsigned vef = (s & 1) ? pw[15] : pw[14];
    unsigned w0 = (s & 2) ? v23 : v01;
    unsigned w1 = (s & 2) ? v67 : v45;
    unsigned w2 = (s & 2) ? vab : v89;
    unsigned w3 = (s & 2) ? vef : vcd;
    unsigned u0 = (s & 4) ? w1 : w0;
    unsigned u1 = (s & 4) ? w3 : w2;
    return (s & 8) ? u1 : u0;
}

__global__ __launch_bounds__(1024) void ebm_main(
    const float* __restrict__ x,
    const int*   __restrict__ pairs,
    const float* __restrict__ tables_f32,
    const float* __restrict__ bias,
    const float* __restrict__ ws,
    const __half* __restrict__ T16,
    int useT16,
    float*       __restrict__ out) {

    // exactly 160 KiB
    __shared__ float  sE[16384];
    __shared__ float  sPE[16384];
    __shared__ float4 sME[1024];
    __shared__ float4 sMP[1024];

    int tid = threadIdx.x;
    {
        const float4* w4 = (const float4*)ws;
        float4* dE = (float4*)sE;
        float4* dP = (float4*)sPE;
        for (int i = tid; i < 4096; i += 1024) {
            dE[i] = w4[i];
            dP[i] = w4[4096 + i];
        }
        if (tid < 1024) {
            sME[tid] = w4[8192 + tid];
            sMP[tid] = w4[9216 + tid];
        }
    }
    const float*  CU = ws + 40960;
    const float*  CP = ws + 41984;
    const __half* Wg = (const __half*)(ws + 43008);
    float bias0 = bias[0];

    __syncthreads();

    int row = blockIdx.x * 1024 + tid;       // 256 blocks x 1024 threads
    const float4* x4 = (const float4*)x + row * 16;
    const float4* sE4 = (const float4*)sE;
    const float4* sP4 = (const float4*)sPE;

    float acc = 0.f;
    unsigned pw[16];

    float4 xg = x4[0];
#pragma unroll
    for (int g = 0; g < 16; ++g) {
        float4 xnext = xg;
        if (g < 15) xnext = x4[g + 1];
        float xf[4] = {xg.x, xg.y, xg.z, xg.w};

        // ---- unary: coarse (SGPR compares) ----
        int t[4];
#pragma unroll
        for (int j = 0; j < 4; ++j) {
            const float* cu = CU + (4 * g + j) * 16;   // uniform -> s_load
            int tt = 0;
#pragma unroll
            for (int k = 0; k < 15; ++k) tt += (xf[j] >= cu[k]);
            t[j] = tt;
        }
        // ---- pair: coarse ----
        int t2[4];
#pragma unroll
        for (int j = 0; j < 4; ++j) {
            const float* cp = CP + (4 * g + j) * 16;
            int tt = 0;
#pragma unroll
            for (int k = 0; k < 15; ++k) tt += (xf[j] >= cp[k]);
            t2[j] = tt;
        }
        // ---- mids (LDS, conflict-free: bank grp = t mod 8 + broadcasts) ----
        float4 mu[4], mp[4];
#pragma unroll
        for (int j = 0; j < 4; ++j) mu[j] = sME[(4 * g + j) * 16 + t[j]];
#pragma unroll
        for (int j = 0; j < 4; ++j) mp[j] = sMP[(4 * g + j) * 16 + t2[j]];
        // ---- fine loads ----
        int lo[4], lo2[4];
        float4 fu[4], fp[4];
#pragma unroll
        for (int j = 0; j < 4; ++j) {
            int m = (xf[j] >= mu[j].x) + (xf[j] >= mu[j].y) + (xf[j] >= mu[j].z);
            lo[j] = 4 * t[j] + m;
            fu[j] = sE4[(4 * g + j) * 64 + lo[j]];
        }
#pragma unroll
        for (int j = 0; j < 4; ++j) {
            int m = (xf[j] >= mp[j].x) + (xf[j] >= mp[j].y) + (xf[j] >= mp[j].z);
            lo2[j] = 4 * t2[j] + m;
            fp[j] = sP4[(4 * g + j) * 64 + lo2[j]];
        }
        // ---- unary consume -> W gather (global fp16, <=8 lines/wave) ----
#pragma unroll
        for (int j = 0; j < 4; ++j) {
            int c = 4 * lo[j] + (xf[j] >= fu[j].x) + (xf[j] >= fu[j].y) +
                    (xf[j] >= fu[j].z) + (xf[j] >= fu[j].w);
            acc += __half2float(Wg[(4 * g + j) * 256 + c]);
        }
        // ---- pair consume -> pack 8-bit ----
        unsigned pword = 0;
#pragma unroll
        for (int j = 0; j < 4; ++j) {
            int c2 = 4 * lo2[j] + (xf[j] >= fp[j].x) + (xf[j] >= fp[j].y) +
                     (xf[j] >= fp[j].z) + (xf[j] >= fp[j].w);
            pword |= (unsigned)c2 << (8 * j);
        }
        pw[g] = pword;
        xg = xnext;
    }

    // ---- pair table gathers: per-lane-owned, no exchange ----
    if (useT16) {
#pragma unroll
        for (int p = 0; p < NPAIRS; ++p) {
            int a = pairs[2 * p], b = pairs[2 * p + 1];   // uniform
            unsigned wa = pick16(pw, a >> 2);
            unsigned wb = pick16(pw, b >> 2);
            int li = (wa >> ((a & 3) * 8)) & 255;
            int ri = (wb >> ((b & 3) * 8)) & 255;
            acc += __half2float(T16[(p << 16) + (li << 8) + ri]);
        }
    } else {
#pragma unroll
        for (int p = 0; p < NPAIRS; ++p) {
            int a = pairs[2 * p], b = pairs[2 * p + 1];
            unsigned wa = pick16(pw, a >> 2);
            unsigned wb = pick16(pw, b >> 2);
            int li = (wa >> ((a & 3) * 8)) & 255;
            int ri = (wb >> ((b & 3) * 8)) & 255;
            int lb = (li < 255) ? li + 1 : 0;
            int rb = (ri < 255) ? ri + 1 : 0;
            acc += tables_f32[(p << 16) + (lb << 8) + rb];
        }
    }

    out[row] = 1.0f / (1.0f + __expf(-(acc + bias0)));
}

extern "C" void kernel_launch(void* const* d_in, const int* in_sizes, int n_in,
                              void* d_out, int out_size, void* d_ws, size_t ws_size,
                              hipStream_t stream) {
    const float* x          = (const float*)d_in[0];
    const float* edges      = (const float*)d_in[1];
    const float* w          = (const float*)d_in[2];
    const float* pair_edges = (const float*)d_in[3];
    const int*   pairs      = (const int*)d_in[4];
    const float* tables     = (const float*)d_in[5];
    const float* bias       = (const float*)d_in[6];
    float* out = (float*)d_out;
    float* ws  = (float*)d_ws;

    int useT16 = (ws_size >= (size_t)4399104) ? 1 : 0;
    __half* T16 = (__half*)((char*)d_ws + 204800);

    ebm_prep<<<64, 256, 0, stream>>>(edges, pair_edges, w, ws);
    if (useT16) {
        ebm_prep_tables<<<2048, 1024, 0, stream>>>(tables, (unsigned short*)T16);
    }
    ebm_main<<<256, 1024, 0, stream>>>(x, pairs, tables, bias, ws, T16, useT16, out);
}